// Round 17
// baseline (115.517 us; speedup 1.0000x reference)
//
#include <hip/hip_runtime.h>
#include <hip/hip_bf16.h>

typedef __attribute__((ext_vector_type(8))) short s16x8;
typedef __attribute__((ext_vector_type(4))) float f32x4;
typedef __attribute__((ext_vector_type(2))) unsigned int u32x2;
typedef __attribute__((ext_vector_type(4))) unsigned int u32x4;

#define MFMA16(a, b, c) __builtin_amdgcn_mfma_f32_16x16x32_bf16((a), (b), (c), 0, 0, 0)
#define LOG2E 1.4426950408889634f

// 16-lane row-rotate via DPP (VALU pipe, no LDS-unit traffic). ror:N = 0x120|N.
#define ROR16(x, CTRL) \
  __int_as_float(__builtin_amdgcn_update_dpp(0, __float_as_int(x), (CTRL), 0xF, 0xF, true))

static __device__ __forceinline__ unsigned int pk2(float a, float b) {
  union { __hip_bfloat162 h2; unsigned int u; } cv;
  cv.h2 = __float22bfloat162_rn(make_float2(a, b));
  return cv.u;
}
static __device__ __forceinline__ int div7(int x) { return (x * 9363) >> 16; }  // exact 0..62
static __device__ __forceinline__ int swz256(int row, int byteoff) {
  return row * 256 + (byteoff ^ ((row & 7) << 4));
}
static __device__ __forceinline__ int swz128(int row, int byteoff) {
  return row * 128 + (byteoff ^ ((row & 7) << 4));
}
// load 8 consecutive fp32 weights -> packed bf16 s16x8 (L2-hot)
static __device__ __forceinline__ s16x8 ldw8(const float* p) {
  f32x4 a = *(const f32x4*)p;
  f32x4 b = *(const f32x4*)(p + 4);
  union { u32x4 u; s16x8 s; } cv;
  cv.u = (u32x4){pk2(a[0], a[1]), pk2(a[2], a[3]), pk2(b[0], b[1]), pk2(b[2], b[3])};
  return cv.s;
}

// ---------- main: one 512-thread WG per (batch, window); single kernel, no prep ----------
// R0 [0,16K): Xq -> Xv -> O ; R1 [16K,32K): Q then P(h=0,1)
// R2 [32K,48K): K then P(h=2,3) ; R3 [48K,64K): Xk then V^T [128ch][64tok]
__global__ __launch_bounds__(512, 4) void swin_main(
    const float* __restrict__ xq, const float* __restrict__ xk, const float* __restrict__ xv,
    const float* __restrict__ wq, const float* __restrict__ bq,
    const float* __restrict__ wk, const float* __restrict__ bk,
    const float* __restrict__ wv, const float* __restrict__ bv,
    const float* __restrict__ wp, const float* __restrict__ bp,
    const float* __restrict__ rpb_table, float* __restrict__ out) {
  __shared__ __align__(16) char sm[65536];

  const int tid = threadIdx.x;
  const int lane = tid & 63;
  const int wv_ = tid >> 6;       // wave 0..7
  const int l15 = lane & 15;
  const int lg = lane >> 4;
  const int kgrp = lg * 8;
  const int rsub = lg * 4;

  const int bid = blockIdx.x;
  const int b = bid >> 6;
  const int widx = bid & 63;
  const int wi = widx >> 3, wj = widx & 7;
  const long obase = (long)b * 56 * 56 * 128;

  const int h = wv_ & 3;
  const int half = wv_ >> 2;
  const int coff = h * 32;

  // ---- X loader geometry ----
  const int xrow = tid >> 3;
  const int xk16 = (tid & 7) << 4;
  long xoff = -1;
  if (xrow < 49) {
    int ty = div7(xrow), tx = xrow - ty * 7;
    int ih = wi * 7 + ty + 3; if (ih >= 56) ih -= 56;
    int iw = wj * 7 + tx + 3; if (iw >= 56) iw -= 56;
    xoff = obase + (long)((ih * 56 + iw) * 128 + xk16);
  }

  auto issue_x = [&](const float* src, float* r) {
#pragma unroll
    for (int i = 0; i < 16; ++i) r[i] = 0.f;
    if (xoff >= 0) {
      const float* p = src + xoff;
#pragma unroll
      for (int q = 0; q < 4; ++q) {
        f32x4 v = *(const f32x4*)(p + q * 4);
        r[q * 4 + 0] = v[0]; r[q * 4 + 1] = v[1];
        r[q * 4 + 2] = v[2]; r[q * 4 + 3] = v[3];
      }
    }
  };
  auto write_x = [&](int base, const float* r) {
    unsigned int w[8];
#pragma unroll
    for (int i = 0; i < 8; ++i) w[i] = pk2(r[2 * i], r[2 * i + 1]);
    u32x4 a = {w[0], w[1], w[2], w[3]};
    u32x4 bb = {w[4], w[5], w[6], w[7]};
    *(u32x4*)(sm + base + swz256(xrow, xk16 * 2)) = a;
    *(u32x4*)(sm + base + swz256(xrow, xk16 * 2 + 16)) = bb;
  };
  auto st2 = [&](int a0, int a1, float v0, float v1) {
    unsigned int u = pk2(v0, v1);
    *(unsigned short*)(sm + a0) = (unsigned short)u;
    *(unsigned short*)(sm + a1) = (unsigned short)(u >> 16);
  };

  // ---- entry: issue X loads FIRST (long-pole HBM latency) ----
  float xra[16], xrb[16];
  issue_x(xq, xra);
  issue_x(xk, xrb);

  // ---- rpb + shift-mask + pad-mask computed in the X-load shadow ----
  // ridx = (yi-yj+6)*13 + (xi-xj+6) = (13*yi+xi) - (13*yj+xj) + 84
  f32x4 rvv[2][4];   // [m2][jt], element r
  {
    const int cwi = (wi == 7), cwj = (wj == 7);
    int jj[4], rgj[4]; bool jv[4];
#pragma unroll
    for (int jt = 0; jt < 4; ++jt) {
      int j = jt * 16 + l15;
      jv[jt] = (j < 49);
      int jc = jv[jt] ? j : 0;
      int yj = div7(jc), xj = jc - yj * 7;
      jj[jt] = yj * 13 + xj;
      rgj[jt] = (cwi ? (yj < 4 ? 3 : 6) : 0) + (cwj ? (xj < 4 ? 1 : 2) : 0);
    }
#pragma unroll
    for (int m2 = 0; m2 < 2; ++m2)
#pragma unroll
      for (int r = 0; r < 4; ++r) {
        int i = (half * 2 + m2) * 16 + rsub + r;
        if (i < 49) {
          int yi = div7(i), xi = i - yi * 7;
          int ri = yi * 13 + xi + 84;
          int rgi = (cwi ? (yi < 4 ? 3 : 6) : 0) + (cwj ? (xi < 4 ? 1 : 2) : 0);
#pragma unroll
          for (int jt = 0; jt < 4; ++jt) {
            float v;
            if (jv[jt]) {
              v = rpb_table[(ri - jj[jt]) * 4 + h];
              if (rgi != rgj[jt]) v -= 100.f;
              v *= LOG2E;
            } else {
              v = -1e30f;
            }
            rvv[m2][jt][r] = v;
          }
        } else {
#pragma unroll
          for (int jt = 0; jt < 4; ++jt)
            rvv[m2][jt][r] = jv[jt] ? 0.f : -1e30f;
        }
      }
  }

  // ---- linearT: D[n][tok] = mfma16(A=W(fp32->bf16), B=X@srcbase) -> row-major dst ----
  auto linearT = [&](const float* w, const float* bias, float scale, int srcbase, int dstbase) {
    const int nrow = wv_ * 16 + l15;
    s16x8 afr[4];
#pragma unroll
    for (int kt = 0; kt < 4; ++kt)
      afr[kt] = ldw8(w + nrow * 128 + kt * 32 + kgrp);
    f32x4 bv4 = *(const f32x4*)(bias + wv_ * 16 + rsub);
    float bb0 = bv4[0] * scale, bb1 = bv4[1] * scale;
    float bb2 = bv4[2] * scale, bb3 = bv4[3] * scale;
    __builtin_amdgcn_s_setprio(1);
#pragma unroll
    for (int tt = 0; tt < 4; ++tt) {
      f32x4 acc = {0.f, 0.f, 0.f, 0.f};
#pragma unroll
      for (int kt = 0; kt < 4; ++kt) {
        s16x8 bfr = *(const s16x8*)(sm + srcbase + swz256(tt * 16 + l15, (kt * 32 + kgrp) * 2));
        acc = MFMA16(afr[kt], bfr, acc);
      }
      u32x2 pkw = {pk2(acc[0] * scale + bb0, acc[1] * scale + bb1),
                   pk2(acc[2] * scale + bb2, acc[3] * scale + bb3)};
      *(u32x2*)(sm + dstbase + swz256(tt * 16 + l15, 2 * (wv_ * 16 + rsub))) = pkw;
    }
    __builtin_amdgcn_s_setprio(0);
  };

  // ---- linearV: D[tok][n] = mfma16(A=X@R0, B=W) -> V^T [ch][tok] at R3 ----
  auto linearV = [&](const float* w, const float* bias) {
    const int n = wv_ * 16 + l15;
    s16x8 bfr[4];
#pragma unroll
    for (int kt = 0; kt < 4; ++kt)
      bfr[kt] = ldw8(w + n * 128 + kt * 32 + kgrp);
    float bval = bias[n];
    __builtin_amdgcn_s_setprio(1);
#pragma unroll
    for (int mt = 0; mt < 4; ++mt) {
      f32x4 acc = {0.f, 0.f, 0.f, 0.f};
#pragma unroll
      for (int kt = 0; kt < 4; ++kt) {
        s16x8 afr = *(const s16x8*)(sm + swz256(mt * 16 + l15, (kt * 32 + kgrp) * 2));
        acc = MFMA16(afr, bfr[kt], acc);
      }
      u32x2 pkw = {pk2(acc[0] + bval, acc[1] + bval), pk2(acc[2] + bval, acc[3] + bval)};
      *(u32x2*)(sm + 49152 + swz128(n, 2 * (mt * 16 + rsub))) = pkw;
    }
    __builtin_amdgcn_s_setprio(0);
  };

  const float QSCALE = 0.17677669529663687f * LOG2E;  // 32^-0.5 * log2(e)

  // ---- entry staging: Xq -> R0 and Xk -> R3 together ----
  write_x(0, xra);
  write_x(49152, xrb);
  __syncthreads();                                    // B1: Xq(R0), Xk(R3)

  issue_x(xv, xra);                                   // Xv loads hide under Q-linear
  linearT(wq, bq, QSCALE, 0, 16384);                  // Q: R0 -> R1
  __syncthreads();                                    // B2: Q done; R0 free

  write_x(0, xra);                                    // Xv -> R0
  linearT(wk, bk, 1.f, 49152, 32768);                 // K: R3 -> R2
  __syncthreads();                                    // B3: Xv(R0), K(R2); R3 free

  // ---- fused: V-linear (R0 -> R3) + QK^T (R1,R2) + DPP softmax ----
  f32x4 S[2][4];
  {
    linearV(wv, bv);

    s16x8 kfr[4];
#pragma unroll
    for (int jt = 0; jt < 4; ++jt)
      kfr[jt] = *(const s16x8*)(sm + 32768 + swz256(jt * 16 + l15, (coff + kgrp) * 2));
    __builtin_amdgcn_s_setprio(1);
#pragma unroll
    for (int m2 = 0; m2 < 2; ++m2) {
      int mt = half * 2 + m2;
      s16x8 qfr = *(const s16x8*)(sm + 16384 + swz256(mt * 16 + l15, (coff + kgrp) * 2));
#pragma unroll
      for (int jt = 0; jt < 4; ++jt)
        S[m2][jt] = MFMA16(qfr, kfr[jt], rvv[m2][jt]);
    }
    __builtin_amdgcn_s_setprio(0);

    // row softmax (base-2), 16-lane reductions on the VALU pipe via DPP row_ror
#pragma unroll
    for (int m2 = 0; m2 < 2; ++m2) {
#pragma unroll
      for (int r = 0; r < 4; ++r) {
        float m = fmaxf(fmaxf(S[m2][0][r], S[m2][1][r]), fmaxf(S[m2][2][r], S[m2][3][r]));
        m = fmaxf(m, ROR16(m, 0x128));
        m = fmaxf(m, ROR16(m, 0x124));
        m = fmaxf(m, ROR16(m, 0x122));
        m = fmaxf(m, ROR16(m, 0x121));
        float e0 = __builtin_amdgcn_exp2f(S[m2][0][r] - m);
        float e1 = __builtin_amdgcn_exp2f(S[m2][1][r] - m);
        float e2 = __builtin_amdgcn_exp2f(S[m2][2][r] - m);
        float e3 = __builtin_amdgcn_exp2f(S[m2][3][r] - m);
        float s = e0 + e1 + e2 + e3;
        s += ROR16(s, 0x128);
        s += ROR16(s, 0x124);
        s += ROR16(s, 0x122);
        s += ROR16(s, 0x121);
        float inv = 1.0f / s;
        S[m2][0][r] = e0 * inv; S[m2][1][r] = e1 * inv;
        S[m2][2][r] = e2 * inv; S[m2][3][r] = e3 * inv;
      }
    }
  }
  __syncthreads();   // B4: V^T complete; all Q/K + Xv reads done

  // ---- P-store (intra-wave) -> PV -> O, no barrier between ----
  const int pbase = 16384 + h * 8192;  // P[64][64] bf16 per head
#pragma unroll
  for (int m2 = 0; m2 < 2; ++m2) {
    int i0 = (half * 2 + m2) * 16 + rsub;
#pragma unroll
    for (int jt = 0; jt < 4; ++jt) {
      int bo = 2 * (jt * 16 + l15);
      st2(pbase + swz128(i0, bo), pbase + swz128(i0 + 1, bo), S[m2][jt][0], S[m2][jt][1]);
      st2(pbase + swz128(i0 + 2, bo), pbase + swz128(i0 + 3, bo), S[m2][jt][2], S[m2][jt][3]);
    }
  }
  {
    // PV : O[q][ch] via D = mfma16(A=V^T, B=P) -> lane = q-token, rows = ch
    s16x8 vfr[2][2];
#pragma unroll
    for (int ks = 0; ks < 2; ++ks)
#pragma unroll
      for (int ct = 0; ct < 2; ++ct) {
        int c = coff + ct * 16 + l15;
        vfr[ks][ct] = *(const s16x8*)(sm + 49152 + swz128(c, (ks * 32 + kgrp) * 2));
      }
    f32x4 Oacc[2][2];   // [ct][qt]
#pragma unroll
    for (int ct = 0; ct < 2; ++ct)
#pragma unroll
      for (int qt = 0; qt < 2; ++qt) Oacc[ct][qt] = (f32x4){0.f, 0.f, 0.f, 0.f};
    __builtin_amdgcn_s_setprio(1);
#pragma unroll
    for (int qt = 0; qt < 2; ++qt) {
#pragma unroll
      for (int ks = 0; ks < 2; ++ks) {
        s16x8 pfr = *(const s16x8*)(sm + pbase + swz128((half * 2 + qt) * 16 + l15, (ks * 32 + kgrp) * 2));
        Oacc[0][qt] = MFMA16(vfr[ks][0], pfr, Oacc[0][qt]);
        Oacc[1][qt] = MFMA16(vfr[ks][1], pfr, Oacc[1][qt]);
      }
    }
    __builtin_amdgcn_s_setprio(0);
    // O row-major [tok][ch] into R0 via b64 writes
#pragma unroll
    for (int ct = 0; ct < 2; ++ct)
#pragma unroll
      for (int qt = 0; qt < 2; ++qt) {
        int qtok = (half * 2 + qt) * 16 + l15;
        u32x2 pkw = {pk2(Oacc[ct][qt][0], Oacc[ct][qt][1]),
                     pk2(Oacc[ct][qt][2], Oacc[ct][qt][3])};
        *(u32x2*)(sm + swz256(qtok, 2 * (coff + ct * 16 + rsub))) = pkw;
      }
  }
  __syncthreads();   // B5: O visible in R0

  // ---- proj: D[n][tok] = mfma16(A=Wp, B=O) -> dwordx4 rolled stores ----
  {
    const int nrow = wv_ * 16 + l15;
    s16x8 afr[4];
#pragma unroll
    for (int kt = 0; kt < 4; ++kt)
      afr[kt] = ldw8(wp + nrow * 128 + kt * 32 + kgrp);
    f32x4 bv4 = *(const f32x4*)(bp + wv_ * 16 + rsub);
    __builtin_amdgcn_s_setprio(1);
#pragma unroll
    for (int tt = 0; tt < 4; ++tt) {
      f32x4 acc = {0.f, 0.f, 0.f, 0.f};
#pragma unroll
      for (int kt = 0; kt < 4; ++kt) {
        s16x8 bfr = *(const s16x8*)(sm + swz256(tt * 16 + l15, (kt * 32 + kgrp) * 2));
        acc = MFMA16(afr[kt], bfr, acc);
      }
      int tok = tt * 16 + l15;
      if (tok < 49) {
        int ty = div7(tok), tx = tok - ty * 7;
        int oh = wi * 7 + ty + 3; if (oh >= 56) oh -= 56;
        int ow = wj * 7 + tx + 3; if (ow >= 56) ow -= 56;
        f32x4 res = {acc[0] + bv4[0], acc[1] + bv4[1], acc[2] + bv4[2], acc[3] + bv4[3]};
        *(f32x4*)(out + obase + (oh * 56 + ow) * 128 + wv_ * 16 + rsub) = res;
      }
    }
    __builtin_amdgcn_s_setprio(0);
  }
}

extern "C" void kernel_launch(void* const* d_in, const int* in_sizes, int n_in,
                              void* d_out, int out_size, void* d_ws, size_t ws_size,
                              hipStream_t stream) {
  const float* xq = (const float*)d_in[0];
  const float* xk = (const float*)d_in[1];
  const float* xv = (const float*)d_in[2];
  const float* wq = (const float*)d_in[3];
  const float* bq = (const float*)d_in[4];
  const float* wk = (const float*)d_in[5];
  const float* bk = (const float*)d_in[6];
  const float* wv = (const float*)d_in[7];
  const float* bv = (const float*)d_in[8];
  const float* wp = (const float*)d_in[9];
  const float* bp = (const float*)d_in[10];
  const float* rpb = (const float*)d_in[11];

  float* out = (float*)d_out;
  swin_main<<<2048, 512, 0, stream>>>(xq, xk, xv, wq, bq, wk, bk, wv, bv, wp, bp, rpb, out);
}

// Round 18
// 75.895 us; speedup vs baseline: 1.5221x; 1.5221x over previous
//
#include <hip/hip_runtime.h>
#include <hip/hip_bf16.h>

typedef __attribute__((ext_vector_type(8))) short s16x8;
typedef __attribute__((ext_vector_type(4))) float f32x4;
typedef __attribute__((ext_vector_type(2))) unsigned int u32x2;
typedef __attribute__((ext_vector_type(4))) unsigned int u32x4;

#define MFMA16(a, b, c) __builtin_amdgcn_mfma_f32_16x16x32_bf16((a), (b), (c), 0, 0, 0)
#define LOG2E 1.4426950408889634f

// 16-lane row-rotate via DPP (VALU pipe, no LDS-unit traffic). ror:N = 0x120|N.
#define ROR16(x, CTRL) \
  __int_as_float(__builtin_amdgcn_update_dpp(0, __float_as_int(x), (CTRL), 0xF, 0xF, true))

static __device__ __forceinline__ unsigned int pk2(float a, float b) {
  union { __hip_bfloat162 h2; unsigned int u; } cv;
  cv.h2 = __float22bfloat162_rn(make_float2(a, b));
  return cv.u;
}
static __device__ __forceinline__ int div7(int x) { return (x * 9363) >> 16; }  // exact 0..62
static __device__ __forceinline__ int swz256(int row, int byteoff) {
  return row * 256 + (byteoff ^ ((row & 7) << 4));
}
static __device__ __forceinline__ int swz128(int row, int byteoff) {
  return row * 128 + (byteoff ^ ((row & 7) << 4));
}

// ---------- prep: weights fp32->bf16 ; rpbm[case][head][64][64] = (rpb + mask)*log2e ----------
__global__ void swin_prep(const float* __restrict__ wq, const float* __restrict__ wk,
                          const float* __restrict__ wv, const float* __restrict__ wp,
                          const float* __restrict__ rpb_table,
                          unsigned short* __restrict__ wsW, float* __restrict__ rpbm) {
  int idx = blockIdx.x * 256 + threadIdx.x;
  if (idx < 65536) {
    int t = idx >> 14, loc = idx & 16383;
    const float* s = (t == 0) ? wq : (t == 1) ? wk : (t == 2) ? wv : wp;
    union { __hip_bfloat16 h; unsigned short u; } cv;
    cv.h = __float2bfloat16(s[loc]);
    wsW[idx] = cv.u;
  } else {
    int k = idx - 65536;               // [case(2b)][head(2b)][i(6b)][j(6b)]
    int c = k >> 14;
    int h = (k >> 12) & 3;
    int i = (k >> 6) & 63, j = k & 63;
    float val;
    if (j >= 49) val = -1e30f;
    else if (i >= 49) val = 0.f;
    else {
      int yi = div7(i), xi = i - yi * 7;
      int yj = div7(j), xj = j - yj * 7;
      int ridx = (yi - yj + 6) * 13 + (xi - xj + 6);
      val = rpb_table[ridx * 4 + h];
      int cwi = c >> 1, cwj = c & 1;
      int rgi = (cwi ? (yi < 4 ? 3 : 6) : 0) + (cwj ? (xi < 4 ? 1 : 2) : 0);
      int rgj = (cwi ? (yj < 4 ? 3 : 6) : 0) + (cwj ? (xj < 4 ? 1 : 2) : 0);
      if (rgi != rgj) val -= 100.f;
      val *= LOG2E;
    }
    rpbm[k] = val;
  }
}

// ---------- main: one 512-thread WG per (batch, window); R14 + setprio on linears ----------
// R0 [0,16K): Xq -> Xv -> O ; R1 [16K,32K): Q then P(h=0,1)
// R2 [32K,48K): K then P(h=2,3) ; R3 [48K,64K): Xk then V^T [128ch][64tok]
__global__ __launch_bounds__(512, 4) void swin_main(
    const float* __restrict__ xq, const float* __restrict__ xk, const float* __restrict__ xv,
    const float* __restrict__ bq, const float* __restrict__ bk, const float* __restrict__ bv,
    const float* __restrict__ bp, const unsigned short* __restrict__ wsW,
    const float* __restrict__ rpbm, float* __restrict__ out) {
  __shared__ __align__(16) char sm[65536];

  const int tid = threadIdx.x;
  const int lane = tid & 63;
  const int wv_ = tid >> 6;       // wave 0..7
  const int l15 = lane & 15;
  const int lg = lane >> 4;
  const int kgrp = lg * 8;
  const int rsub = lg * 4;

  const int bid = blockIdx.x;
  const int b = bid >> 6;
  const int widx = bid & 63;
  const int wi = widx >> 3, wj = widx & 7;
  const long obase = (long)b * 56 * 56 * 128;
  const int mcase = ((wi == 7) ? 2 : 0) + ((wj == 7) ? 1 : 0);

  const int h = wv_ & 3;
  const int half = wv_ >> 2;
  const int coff = h * 32;

  // ---- X loader geometry ----
  const int xrow = tid >> 3;
  const int xk16 = (tid & 7) << 4;
  long xoff = -1;
  if (xrow < 49) {
    int ty = div7(xrow), tx = xrow - ty * 7;
    int ih = wi * 7 + ty + 3; if (ih >= 56) ih -= 56;
    int iw = wj * 7 + tx + 3; if (iw >= 56) iw -= 56;
    xoff = obase + (long)((ih * 56 + iw) * 128 + xk16);
  }

  auto issue_x = [&](const float* src, float* r) {
#pragma unroll
    for (int i = 0; i < 16; ++i) r[i] = 0.f;
    if (xoff >= 0) {
      const float* p = src + xoff;
#pragma unroll
      for (int q = 0; q < 4; ++q) {
        f32x4 v = *(const f32x4*)(p + q * 4);
        r[q * 4 + 0] = v[0]; r[q * 4 + 1] = v[1];
        r[q * 4 + 2] = v[2]; r[q * 4 + 3] = v[3];
      }
    }
  };
  auto write_x = [&](int base, const float* r) {
    unsigned int w[8];
#pragma unroll
    for (int i = 0; i < 8; ++i) w[i] = pk2(r[2 * i], r[2 * i + 1]);
    u32x4 a = {w[0], w[1], w[2], w[3]};
    u32x4 bb = {w[4], w[5], w[6], w[7]};
    *(u32x4*)(sm + base + swz256(xrow, xk16 * 2)) = a;
    *(u32x4*)(sm + base + swz256(xrow, xk16 * 2 + 16)) = bb;
  };
  auto st2 = [&](int a0, int a1, float v0, float v1) {
    unsigned int u = pk2(v0, v1);
    *(unsigned short*)(sm + a0) = (unsigned short)u;
    *(unsigned short*)(sm + a1) = (unsigned short)(u >> 16);
  };

  // ---- entry: issue X loads FIRST (long-pole latency), then L2-hot rpbm loads ----
  float xra[16], xrb[16];
  issue_x(xq, xra);
  issue_x(xk, xrb);

  f32x4 rvv[2][4];   // [m2][jt], element r
  {
    const float* rpbm_h = rpbm + (((mcase << 2) + h) << 12);
#pragma unroll
    for (int m2 = 0; m2 < 2; ++m2)
#pragma unroll
      for (int r = 0; r < 4; ++r) {
        int i = (half * 2 + m2) * 16 + rsub + r;
        const float* rp = rpbm_h + i * 64 + l15;
#pragma unroll
        for (int jt = 0; jt < 4; ++jt) rvv[m2][jt][r] = rp[jt * 16];
      }
  }

  // ---- linearT: D[n][tok] = mfma16(A=W, B=X@srcbase) -> row-major dst via b64 writes ----
  auto linearT = [&](int woff, const float* bias, float scale, int srcbase, int dstbase) {
    const int nrow = wv_ * 16 + l15;
    s16x8 afr[4];
#pragma unroll
    for (int kt = 0; kt < 4; ++kt)
      afr[kt] = *(const s16x8*)(wsW + woff + nrow * 128 + kt * 32 + kgrp);
    f32x4 bv4 = *(const f32x4*)(bias + wv_ * 16 + rsub);
    float bb0 = bv4[0] * scale, bb1 = bv4[1] * scale;
    float bb2 = bv4[2] * scale, bb3 = bv4[3] * scale;
    __builtin_amdgcn_s_setprio(1);
#pragma unroll
    for (int tt = 0; tt < 4; ++tt) {
      f32x4 acc = {0.f, 0.f, 0.f, 0.f};
#pragma unroll
      for (int kt = 0; kt < 4; ++kt) {
        s16x8 bfr = *(const s16x8*)(sm + srcbase + swz256(tt * 16 + l15, (kt * 32 + kgrp) * 2));
        acc = MFMA16(afr[kt], bfr, acc);
      }
      u32x2 pkw = {pk2(acc[0] * scale + bb0, acc[1] * scale + bb1),
                   pk2(acc[2] * scale + bb2, acc[3] * scale + bb3)};
      *(u32x2*)(sm + dstbase + swz256(tt * 16 + l15, 2 * (wv_ * 16 + rsub))) = pkw;
    }
    __builtin_amdgcn_s_setprio(0);
  };

  // ---- linearV: D[tok][n] = mfma16(A=X@R0, B=W) -> V^T [ch][tok] at R3 via b64 writes ----
  auto linearV = [&](int woff, const float* bias) {
    const int n = wv_ * 16 + l15;
    s16x8 bfr[4];
#pragma unroll
    for (int kt = 0; kt < 4; ++kt)
      bfr[kt] = *(const s16x8*)(wsW + woff + n * 128 + kt * 32 + kgrp);
    float bval = bias[n];
    __builtin_amdgcn_s_setprio(1);
#pragma unroll
    for (int mt = 0; mt < 4; ++mt) {
      f32x4 acc = {0.f, 0.f, 0.f, 0.f};
#pragma unroll
      for (int kt = 0; kt < 4; ++kt) {
        s16x8 afr = *(const s16x8*)(sm + swz256(mt * 16 + l15, (kt * 32 + kgrp) * 2));
        acc = MFMA16(afr, bfr[kt], acc);
      }
      u32x2 pkw = {pk2(acc[0] + bval, acc[1] + bval), pk2(acc[2] + bval, acc[3] + bval)};
      *(u32x2*)(sm + 49152 + swz128(n, 2 * (mt * 16 + rsub))) = pkw;
    }
    __builtin_amdgcn_s_setprio(0);
  };

  const float QSCALE = 0.17677669529663687f * LOG2E;  // 32^-0.5 * log2(e)

  // ---- entry staging: Xq -> R0 and Xk -> R3 together ----
  write_x(0, xra);
  write_x(49152, xrb);
  __syncthreads();                                    // B1: Xq(R0), Xk(R3)

  issue_x(xv, xra);                                   // Xv loads hide under Q-linear
  linearT(0, bq, QSCALE, 0, 16384);                   // Q: R0 -> R1
  __syncthreads();                                    // B2: Q done; R0 free

  write_x(0, xra);                                    // Xv -> R0
  linearT(16384, bk, 1.f, 49152, 32768);              // K: R3 -> R2
  __syncthreads();                                    // B3: Xv(R0), K(R2); R3 free

  // ---- fused: V-linear (R0 -> R3) + QK^T (R1,R2) + DPP softmax ----
  f32x4 S[2][4];
  {
    linearV(32768, bv);

    s16x8 kfr[4];
#pragma unroll
    for (int jt = 0; jt < 4; ++jt)
      kfr[jt] = *(const s16x8*)(sm + 32768 + swz256(jt * 16 + l15, (coff + kgrp) * 2));
    __builtin_amdgcn_s_setprio(1);
#pragma unroll
    for (int m2 = 0; m2 < 2; ++m2) {
      int mt = half * 2 + m2;
      s16x8 qfr = *(const s16x8*)(sm + 16384 + swz256(mt * 16 + l15, (coff + kgrp) * 2));
#pragma unroll
      for (int jt = 0; jt < 4; ++jt)
        S[m2][jt] = MFMA16(qfr, kfr[jt], rvv[m2][jt]);
    }
    __builtin_amdgcn_s_setprio(0);

    // row softmax (base-2), 16-lane reductions on the VALU pipe via DPP row_ror
#pragma unroll
    for (int m2 = 0; m2 < 2; ++m2) {
#pragma unroll
      for (int r = 0; r < 4; ++r) {
        float m = fmaxf(fmaxf(S[m2][0][r], S[m2][1][r]), fmaxf(S[m2][2][r], S[m2][3][r]));
        m = fmaxf(m, ROR16(m, 0x128));
        m = fmaxf(m, ROR16(m, 0x124));
        m = fmaxf(m, ROR16(m, 0x122));
        m = fmaxf(m, ROR16(m, 0x121));
        float e0 = __builtin_amdgcn_exp2f(S[m2][0][r] - m);
        float e1 = __builtin_amdgcn_exp2f(S[m2][1][r] - m);
        float e2 = __builtin_amdgcn_exp2f(S[m2][2][r] - m);
        float e3 = __builtin_amdgcn_exp2f(S[m2][3][r] - m);
        float s = e0 + e1 + e2 + e3;
        s += ROR16(s, 0x128);
        s += ROR16(s, 0x124);
        s += ROR16(s, 0x122);
        s += ROR16(s, 0x121);
        float inv = 1.0f / s;
        S[m2][0][r] = e0 * inv; S[m2][1][r] = e1 * inv;
        S[m2][2][r] = e2 * inv; S[m2][3][r] = e3 * inv;
      }
    }
  }
  __syncthreads();   // B4: V^T complete; all Q/K + Xv reads done

  // ---- P-store (intra-wave) -> PV -> O, no barrier between ----
  const int pbase = 16384 + h * 8192;  // P[64][64] bf16 per head
#pragma unroll
  for (int m2 = 0; m2 < 2; ++m2) {
    int i0 = (half * 2 + m2) * 16 + rsub;
#pragma unroll
    for (int jt = 0; jt < 4; ++jt) {
      int bo = 2 * (jt * 16 + l15);
      st2(pbase + swz128(i0, bo), pbase + swz128(i0 + 1, bo), S[m2][jt][0], S[m2][jt][1]);
      st2(pbase + swz128(i0 + 2, bo), pbase + swz128(i0 + 3, bo), S[m2][jt][2], S[m2][jt][3]);
    }
  }
  {
    // PV : O[q][ch] via D = mfma16(A=V^T, B=P) -> lane = q-token, rows = ch
    s16x8 vfr[2][2];
#pragma unroll
    for (int ks = 0; ks < 2; ++ks)
#pragma unroll
      for (int ct = 0; ct < 2; ++ct) {
        int c = coff + ct * 16 + l15;
        vfr[ks][ct] = *(const s16x8*)(sm + 49152 + swz128(c, (ks * 32 + kgrp) * 2));
      }
    f32x4 Oacc[2][2];   // [ct][qt]
#pragma unroll
    for (int ct = 0; ct < 2; ++ct)
#pragma unroll
      for (int qt = 0; qt < 2; ++qt) Oacc[ct][qt] = (f32x4){0.f, 0.f, 0.f, 0.f};
    __builtin_amdgcn_s_setprio(1);
#pragma unroll
    for (int qt = 0; qt < 2; ++qt) {
#pragma unroll
      for (int ks = 0; ks < 2; ++ks) {
        s16x8 pfr = *(const s16x8*)(sm + pbase + swz128((half * 2 + qt) * 16 + l15, (ks * 32 + kgrp) * 2));
        Oacc[0][qt] = MFMA16(vfr[ks][0], pfr, Oacc[0][qt]);
        Oacc[1][qt] = MFMA16(vfr[ks][1], pfr, Oacc[1][qt]);
      }
    }
    __builtin_amdgcn_s_setprio(0);
    // O row-major [tok][ch] into R0 via b64 writes
#pragma unroll
    for (int ct = 0; ct < 2; ++ct)
#pragma unroll
      for (int qt = 0; qt < 2; ++qt) {
        int qtok = (half * 2 + qt) * 16 + l15;
        u32x2 pkw = {pk2(Oacc[ct][qt][0], Oacc[ct][qt][1]),
                     pk2(Oacc[ct][qt][2], Oacc[ct][qt][3])};
        *(u32x2*)(sm + swz256(qtok, 2 * (coff + ct * 16 + rsub))) = pkw;
      }
  }
  __syncthreads();   // B5: O visible in R0

  // ---- proj: D[n][tok] = mfma16(A=Wp, B=O) -> dwordx4 rolled stores ----
  {
    const int nrow = wv_ * 16 + l15;
    s16x8 afr[4];
#pragma unroll
    for (int kt = 0; kt < 4; ++kt)
      afr[kt] = *(const s16x8*)(wsW + 49152 + nrow * 128 + kt * 32 + kgrp);
    f32x4 bv4 = *(const f32x4*)(bp + wv_ * 16 + rsub);
    __builtin_amdgcn_s_setprio(1);
#pragma unroll
    for (int tt = 0; tt < 4; ++tt) {
      f32x4 acc = {0.f, 0.f, 0.f, 0.f};
#pragma unroll
      for (int kt = 0; kt < 4; ++kt) {
        s16x8 bfr = *(const s16x8*)(sm + swz256(tt * 16 + l15, (kt * 32 + kgrp) * 2));
        acc = MFMA16(afr[kt], bfr, acc);
      }
      int tok = tt * 16 + l15;
      if (tok < 49) {
        int ty = div7(tok), tx = tok - ty * 7;
        int oh = wi * 7 + ty + 3; if (oh >= 56) oh -= 56;
        int ow = wj * 7 + tx + 3; if (ow >= 56) ow -= 56;
        f32x4 res = {acc[0] + bv4[0], acc[1] + bv4[1], acc[2] + bv4[2], acc[3] + bv4[3]};
        *(f32x4*)(out + obase + (oh * 56 + ow) * 128 + wv_ * 16 + rsub) = res;
      }
    }
    __builtin_amdgcn_s_setprio(0);
  }
}

extern "C" void kernel_launch(void* const* d_in, const int* in_sizes, int n_in,
                              void* d_out, int out_size, void* d_ws, size_t ws_size,
                              hipStream_t stream) {
  const float* xq = (const float*)d_in[0];
  const float* xk = (const float*)d_in[1];
  const float* xv = (const float*)d_in[2];
  const float* wq = (const float*)d_in[3];
  const float* bq = (const float*)d_in[4];
  const float* wk = (const float*)d_in[5];
  const float* bk = (const float*)d_in[6];
  const float* wv = (const float*)d_in[7];
  const float* bv = (const float*)d_in[8];
  const float* wp = (const float*)d_in[9];
  const float* bp = (const float*)d_in[10];
  const float* rpb = (const float*)d_in[11];

  unsigned short* wsW = (unsigned short*)d_ws;          // 4 x 16384 bf16 = 128 KB
  float* rpbm = (float*)((char*)d_ws + 131072);         // 4*4*64*64 f32 = 256 KB

  swin_prep<<<512, 256, 0, stream>>>(wq, wk, wv, wp, rpb, wsW, rpbm);

  float* out = (float*)d_out;
  swin_main<<<2048, 512, 0, stream>>>(xq, xk, xv, bq, bk, bv, bp, wsW, rpbm, out);
}